// Round 1
// baseline (294.806 us; speedup 1.0000x reference)
//
#include <hip/hip_runtime.h>
#include <hip/hip_bf16.h>
#include <math.h>

// Problem constants (from reference)
#define BB 512
#define SS 4096
#define DD 128
#define VV 6
#define KK 409   // max(1, int(4096*0.1))

// d_ws layout (floats): [0..5] score_t ; [16..16+6*128) att_t rows (64B aligned)

__global__ void precompute_kernel(
    const float* __restrict__ emb,
    const float* __restrict__ W1, const float* __restrict__ b1,
    const float* __restrict__ W2, const float* __restrict__ b2,
    const float* __restrict__ W3, const float* __restrict__ b3,
    const float* __restrict__ A1, const float* __restrict__ a1,
    const float* __restrict__ A2, const float* __restrict__ a2,
    float* __restrict__ ws)
{
    __shared__ float e[DD];
    __shared__ float h1[64];
    __shared__ float g[64];
    __shared__ float h2[32];
    const int tid = threadIdx.x;  // 128 threads
    float* ws_scores = ws;
    float* ws_att    = ws + 16;

    for (int t = 0; t < VV; ++t) {
        if (tid < DD) e[tid] = emb[t*DD + tid];
        __syncthreads();
        if (tid < 64) {
            float acc1 = b1[tid];
            float accg = a1[tid];
            for (int d = 0; d < DD; ++d) {
                float ed = e[d];
                acc1 += ed * W1[d*64 + tid];
                accg += ed * A1[d*64 + tid];
            }
            h1[tid] = fmaxf(acc1, 0.f);
            g[tid]  = fmaxf(accg, 0.f);
        }
        __syncthreads();
        if (tid < 32) {
            float acc = b2[tid];
            for (int j = 0; j < 64; ++j) acc += h1[j] * W2[j*32 + tid];
            h2[tid] = fmaxf(acc, 0.f);
        }
        __syncthreads();
        if (tid == 0) {
            float s = b3[0];
            for (int j = 0; j < 32; ++j) s += h2[j] * W3[j];
            ws_scores[t] = 1.f / (1.f + expf(-s));
        }
        if (tid < DD) {
            float acc = a2[tid];
            for (int j = 0; j < 64; ++j) acc += g[j] * A2[j*DD + tid];
            ws_att[t*DD + tid] = acc;
        }
        __syncthreads();
    }
}

__global__ __launch_bounds__(256) void row_kernel(
    const int* __restrict__ x,
    const float* __restrict__ ws,
    const float* __restrict__ C1, const float* __restrict__ c1,
    const float* __restrict__ C2, const float* __restrict__ c2,
    float* __restrict__ pred, float* __restrict__ topk, float* __restrict__ fsc)
{
    __shared__ float sc[VV];
    __shared__ float att_s[VV*DD];
    __shared__ int   waveTot[4*VV];
    __shared__ float pooled[DD];
    __shared__ float hcls[64];

    const int tid  = threadIdx.x;
    const int b    = blockIdx.x;
    const int lane = tid & 63;
    const int w    = tid >> 6;

    if (tid < VV) sc[tid] = ws[tid];
    for (int i = tid; i < VV*DD; i += 256) att_s[i] = ws[16 + i];
    __syncthreads();

    // ---- pass 1: load 16 contiguous tokens per thread, write scores, local hist
    const int base = b*SS + tid*16;
    int vals[16];
    const int4* xp = (const int4*)(x + base);
    #pragma unroll
    for (int q = 0; q < 4; ++q) {
        int4 v = xp[q];
        vals[q*4+0]=v.x; vals[q*4+1]=v.y; vals[q*4+2]=v.z; vals[q*4+3]=v.w;
    }
    float4* op = (float4*)(fsc + base);
    #pragma unroll
    for (int q = 0; q < 4; ++q) {
        float4 o;
        o.x = sc[vals[q*4+0]];
        o.y = sc[vals[q*4+1]];
        o.z = sc[vals[q*4+2]];
        o.w = sc[vals[q*4+3]];
        op[q] = o;
    }
    int lc[VV];
    #pragma unroll
    for (int t = 0; t < VV; ++t) {
        int c = 0;
        #pragma unroll
        for (int i = 0; i < 16; ++i) c += (vals[i] == t) ? 1 : 0;
        lc[t] = c;
    }

    // ---- per-wave inclusive scan per token, cross-wave totals
    int excl[VV];
    #pragma unroll
    for (int t = 0; t < VV; ++t) {
        int v = lc[t];
        #pragma unroll
        for (int off = 1; off < 64; off <<= 1) {
            int u = __shfl_up(v, off, 64);
            if (lane >= off) v += u;
        }
        excl[t] = v - lc[t];
        if (lane == 63) waveTot[w*VV + t] = v;
    }
    __syncthreads();

    int rowTot[VV], woff[VV];
    #pragma unroll
    for (int t = 0; t < VV; ++t) {
        int a0 = waveTot[0*VV+t], a1v = waveTot[1*VV+t];
        int a2v = waveTot[2*VV+t], a3v = waveTot[3*VV+t];
        rowTot[t] = a0 + a1v + a2v + a3v;
        int wo = 0;
        if (w > 0) wo += a0;
        if (w > 1) wo += a1v;
        if (w > 2) wo += a2v;
        woff[t] = wo;
    }

    // ---- token priority by (score desc, index asc); all compile-time indexing
    float s_reg[VV];
    #pragma unroll
    for (int t = 0; t < VV; ++t) s_reg[t] = sc[t];
    int pri[VV];
    #pragma unroll
    for (int t = 0; t < VV; ++t) {
        int p = 0;
        #pragma unroll
        for (int u = 0; u < VV; ++u)
            p += ((s_reg[u] > s_reg[t]) || ((s_reg[u] == s_reg[t]) && (u < t))) ? 1 : 0;
        pri[t] = p;
    }
    int start[VV], m[VV];
    #pragma unroll
    for (int t = 0; t < VV; ++t) {
        int cb = 0;
        #pragma unroll
        for (int u = 0; u < VV; ++u)
            cb += (pri[u] < pri[t]) ? rowTot[u] : 0;
        int mm = KK - cb;
        mm = (mm < 0) ? 0 : mm;
        mm = (mm > rowTot[t]) ? rowTot[t] : mm;
        m[t] = mm;
        start[t] = cb + woff[t] + excl[t];
    }

    // ---- pass 2: emit selected indices (token-outer to keep register indexing static)
    #pragma unroll
    for (int t = 0; t < VV; ++t) {
        int pos = start[t];
        #pragma unroll
        for (int i = 0; i < 16; ++i) {
            if (vals[i] == t) {
                if (pos < KK) topk[b*KK + pos] = (float)(tid*16 + i);
                pos++;
            }
        }
    }

    // ---- pooled = sum_t m_t * att_t / K ; classifier MLP
    if (tid < DD) {
        float acc = 0.f;
        #pragma unroll
        for (int t = 0; t < VV; ++t) acc += (float)m[t] * att_s[t*DD + tid];
        pooled[tid] = acc * (1.0f / (float)KK);
    }
    __syncthreads();
    if (tid < 64) {
        float acc = c1[tid];
        for (int d = 0; d < DD; ++d) acc += pooled[d] * C1[d*64 + tid];
        hcls[tid] = fmaxf(acc, 0.f);
    }
    __syncthreads();
    if (tid == 0) {
        float s = c2[0];
        for (int j = 0; j < 64; ++j) s += hcls[j] * C2[j];
        pred[b] = 1.f / (1.f + expf(-s));
    }
}

extern "C" void kernel_launch(void* const* d_in, const int* in_sizes, int n_in,
                              void* d_out, int out_size, void* d_ws, size_t ws_size,
                              hipStream_t stream)
{
    (void)in_sizes; (void)n_in; (void)out_size; (void)ws_size;
    const int*   x   = (const int*)d_in[0];
    const float* emb = (const float*)d_in[1];
    const float* W1  = (const float*)d_in[2];
    const float* b1  = (const float*)d_in[3];
    const float* W2  = (const float*)d_in[4];
    const float* b2  = (const float*)d_in[5];
    const float* W3  = (const float*)d_in[6];
    const float* b3  = (const float*)d_in[7];
    const float* A1  = (const float*)d_in[8];
    const float* a1  = (const float*)d_in[9];
    const float* A2  = (const float*)d_in[10];
    const float* a2  = (const float*)d_in[11];
    const float* C1  = (const float*)d_in[12];
    const float* c1  = (const float*)d_in[13];
    const float* C2  = (const float*)d_in[14];
    const float* c2  = (const float*)d_in[15];

    float* out  = (float*)d_out;
    float* pred = out;                 // [B]
    float* topk = out + BB;            // [B,K] (indices written as float32 — exact)
    float* fsc  = out + BB + BB*KK;    // [B,S]
    float* ws   = (float*)d_ws;

    precompute_kernel<<<1, 128, 0, stream>>>(emb, W1, b1, W2, b2, W3, b3,
                                             A1, a1, A2, a2, ws);
    row_kernel<<<BB, 256, 0, stream>>>(x, ws, C1, c1, C2, c2, pred, topk, fsc);
}

// Round 2
// 116.653 us; speedup vs baseline: 2.5272x; 2.5272x over previous
//
#include <hip/hip_runtime.h>
#include <hip/hip_bf16.h>
#include <math.h>

// Problem constants (from reference)
#define BB 512
#define SS 4096
#define DD 128
#define VV 6
#define KK 409   // max(1, int(4096*0.1))

// d_ws layout (floats): [0..5] score_t ; [16..16+6*128) att_t rows (64B aligned)

// R1: LDS-staged precompute. R0's version was 225 us (VALUBusy 0.002%):
// rolled 128-iter loops of strided global loads = serial ~250cyc latency each.
// Now: one wide float4 copy of all weights (~115 KB) into LDS (pipelined,
// ~5 us), then flat unit-parallel compute from LDS (~2 us).
__global__ __launch_bounds__(256) void precompute_kernel(
    const float* __restrict__ emb,
    const float* __restrict__ W1, const float* __restrict__ b1,
    const float* __restrict__ W2, const float* __restrict__ b2,
    const float* __restrict__ W3, const float* __restrict__ b3,
    const float* __restrict__ A1, const float* __restrict__ a1,
    const float* __restrict__ A2, const float* __restrict__ a2,
    float* __restrict__ ws)
{
    __shared__ float sW1[DD * 64];   // 8192
    __shared__ float sA1[DD * 64];   // 8192
    __shared__ float sW2[64 * 32];   // 2048
    __shared__ float sA2[64 * DD];   // 8192
    __shared__ float sE[VV * DD];    // 768
    __shared__ float sW3[32];
    __shared__ float sb1[64], sb2[32], sa1[64], sa2[DD];
    __shared__ float sh1[VV * 64], sg[VV * 64], sh2[VV * 32];
    __shared__ float sb3;

    const int tid = threadIdx.x; // 256 threads

    // cooperative float4 staging (all sizes %4==0, device allocs are 16B-aligned)
    {
        const float* srcs[9] = { W1, A1, W2, A2, emb, b1, b2, a1, a2 };
        float*       dsts[9] = { sW1, sA1, sW2, sA2, sE, sb1, sb2, sa1, sa2 };
        const int    ns[9]   = { 8192, 8192, 2048, 8192, VV*DD, 64, 32, 64, DD };
        for (int a = 0; a < 9; ++a) {
            const float4* s4 = (const float4*)srcs[a];
            float4* d4 = (float4*)dsts[a];
            const int n4 = ns[a] >> 2;
            for (int i = tid; i < n4; i += 256) d4[i] = s4[i];
        }
        if (tid < 32) sW3[tid] = W3[tid];
        if (tid == 0) sb3 = b3[0];
    }
    __syncthreads();

    // phase 1: h1[t][o] and g[t][o] — 2*6*64 = 768 units
    for (int u = tid; u < 768; u += 256) {
        const int isH = (u < 384) ? 1 : 0;
        const int v = isH ? u : (u - 384);
        const int t = v >> 6, o = v & 63;
        const float* wcol = isH ? sW1 : sA1;
        float acc = isH ? sb1[o] : sa1[o];
        const float* ev = &sE[t * DD];
        #pragma unroll 8
        for (int d = 0; d < DD; ++d) acc += ev[d] * wcol[d * 64 + o];
        acc = fmaxf(acc, 0.f);
        if (isH) sh1[v] = acc; else sg[v] = acc;
    }
    __syncthreads();

    // phase 2: h2[t][o] — 6*32 = 192 units
    for (int u = tid; u < VV * 32; u += 256) {
        const int t = u >> 5, o = u & 31;
        float acc = sb2[o];
        #pragma unroll 8
        for (int j = 0; j < 64; ++j) acc += sh1[t * 64 + j] * sW2[j * 32 + o];
        sh2[u] = fmaxf(acc, 0.f);
    }
    __syncthreads();

    // phase 3: scores (6 units) + att rows (6*128 = 768 units)
    for (int u = tid; u < 6 + VV * DD; u += 256) {
        if (u < 6) {
            float s = sb3;
            #pragma unroll
            for (int j = 0; j < 32; ++j) s += sh2[u * 32 + j] * sW3[j];
            ws[u] = 1.f / (1.f + expf(-s));
        } else {
            const int v = u - 6;
            const int t = v >> 7, o = v & 127;
            float acc = sa2[o];
            #pragma unroll 8
            for (int j = 0; j < 64; ++j) acc += sg[t * 64 + j] * sA2[j * DD + o];
            ws[16 + v] = acc;
        }
    }
}

__global__ __launch_bounds__(256) void row_kernel(
    const int* __restrict__ x,
    const float* __restrict__ ws,
    const float* __restrict__ C1, const float* __restrict__ c1,
    const float* __restrict__ C2, const float* __restrict__ c2,
    float* __restrict__ pred, float* __restrict__ topk, float* __restrict__ fsc)
{
    __shared__ float sc[VV];
    __shared__ float att_s[VV*DD];
    __shared__ int   waveTot[4*VV];
    __shared__ float pooled[DD];
    __shared__ float hcls[64];

    const int tid  = threadIdx.x;
    const int b    = blockIdx.x;
    const int lane = tid & 63;
    const int w    = tid >> 6;

    if (tid < VV) sc[tid] = ws[tid];
    for (int i = tid; i < VV*DD; i += 256) att_s[i] = ws[16 + i];
    __syncthreads();

    // ---- pass 1: load 16 contiguous tokens per thread, write scores, local hist
    const int base = b*SS + tid*16;
    int vals[16];
    const int4* xp = (const int4*)(x + base);
    #pragma unroll
    for (int q = 0; q < 4; ++q) {
        int4 v = xp[q];
        vals[q*4+0]=v.x; vals[q*4+1]=v.y; vals[q*4+2]=v.z; vals[q*4+3]=v.w;
    }
    float4* op = (float4*)(fsc + base);
    #pragma unroll
    for (int q = 0; q < 4; ++q) {
        float4 o;
        o.x = sc[vals[q*4+0]];
        o.y = sc[vals[q*4+1]];
        o.z = sc[vals[q*4+2]];
        o.w = sc[vals[q*4+3]];
        op[q] = o;
    }
    int lc[VV];
    #pragma unroll
    for (int t = 0; t < VV; ++t) {
        int c = 0;
        #pragma unroll
        for (int i = 0; i < 16; ++i) c += (vals[i] == t) ? 1 : 0;
        lc[t] = c;
    }

    // ---- per-wave inclusive scan per token, cross-wave totals
    int excl[VV];
    #pragma unroll
    for (int t = 0; t < VV; ++t) {
        int v = lc[t];
        #pragma unroll
        for (int off = 1; off < 64; off <<= 1) {
            int u = __shfl_up(v, off, 64);
            if (lane >= off) v += u;
        }
        excl[t] = v - lc[t];
        if (lane == 63) waveTot[w*VV + t] = v;
    }
    __syncthreads();

    int rowTot[VV], woff[VV];
    #pragma unroll
    for (int t = 0; t < VV; ++t) {
        int a0 = waveTot[0*VV+t], a1v = waveTot[1*VV+t];
        int a2v = waveTot[2*VV+t], a3v = waveTot[3*VV+t];
        rowTot[t] = a0 + a1v + a2v + a3v;
        int wo = 0;
        if (w > 0) wo += a0;
        if (w > 1) wo += a1v;
        if (w > 2) wo += a2v;
        woff[t] = wo;
    }

    // ---- token priority by (score desc, index asc); all compile-time indexing
    float s_reg[VV];
    #pragma unroll
    for (int t = 0; t < VV; ++t) s_reg[t] = sc[t];
    int pri[VV];
    #pragma unroll
    for (int t = 0; t < VV; ++t) {
        int p = 0;
        #pragma unroll
        for (int u = 0; u < VV; ++u)
            p += ((s_reg[u] > s_reg[t]) || ((s_reg[u] == s_reg[t]) && (u < t))) ? 1 : 0;
        pri[t] = p;
    }
    int start[VV], m[VV];
    #pragma unroll
    for (int t = 0; t < VV; ++t) {
        int cb = 0;
        #pragma unroll
        for (int u = 0; u < VV; ++u)
            cb += (pri[u] < pri[t]) ? rowTot[u] : 0;
        int mm = KK - cb;
        mm = (mm < 0) ? 0 : mm;
        mm = (mm > rowTot[t]) ? rowTot[t] : mm;
        m[t] = mm;
        start[t] = cb + woff[t] + excl[t];
    }

    // ---- pass 2: emit selected indices (token-outer to keep register indexing static)
    #pragma unroll
    for (int t = 0; t < VV; ++t) {
        int pos = start[t];
        #pragma unroll
        for (int i = 0; i < 16; ++i) {
            if (vals[i] == t) {
                if (pos < KK) topk[b*KK + pos] = (float)(tid*16 + i);
                pos++;
            }
        }
    }

    // ---- pooled = sum_t m_t * att_t / K ; classifier MLP
    if (tid < DD) {
        float acc = 0.f;
        #pragma unroll
        for (int t = 0; t < VV; ++t) acc += (float)m[t] * att_s[t*DD + tid];
        pooled[tid] = acc * (1.0f / (float)KK);
    }
    __syncthreads();
    if (tid < 64) {
        float acc = c1[tid];
        for (int d = 0; d < DD; ++d) acc += pooled[d] * C1[d*64 + tid];
        hcls[tid] = fmaxf(acc, 0.f);
    }
    __syncthreads();
    if (tid == 0) {
        float s = c2[0];
        for (int j = 0; j < 64; ++j) s += hcls[j] * C2[j];
        pred[b] = 1.f / (1.f + expf(-s));
    }
}

extern "C" void kernel_launch(void* const* d_in, const int* in_sizes, int n_in,
                              void* d_out, int out_size, void* d_ws, size_t ws_size,
                              hipStream_t stream)
{
    (void)in_sizes; (void)n_in; (void)out_size; (void)ws_size;
    const int*   x   = (const int*)d_in[0];
    const float* emb = (const float*)d_in[1];
    const float* W1  = (const float*)d_in[2];
    const float* b1  = (const float*)d_in[3];
    const float* W2  = (const float*)d_in[4];
    const float* b2  = (const float*)d_in[5];
    const float* W3  = (const float*)d_in[6];
    const float* b3  = (const float*)d_in[7];
    const float* A1  = (const float*)d_in[8];
    const float* a1  = (const float*)d_in[9];
    const float* A2  = (const float*)d_in[10];
    const float* a2  = (const float*)d_in[11];
    const float* C1  = (const float*)d_in[12];
    const float* c1  = (const float*)d_in[13];
    const float* C2  = (const float*)d_in[14];
    const float* c2  = (const float*)d_in[15];

    float* out  = (float*)d_out;
    float* pred = out;                 // [B]
    float* topk = out + BB;            // [B,K] (indices written as float32 — exact)
    float* fsc  = out + BB + BB*KK;    // [B,S]
    float* ws   = (float*)d_ws;

    precompute_kernel<<<1, 256, 0, stream>>>(emb, W1, b1, W2, b2, W3, b3,
                                             A1, a1, A2, a2, ws);
    row_kernel<<<BB, 256, 0, stream>>>(x, ws, C1, c1, C2, c2, pred, topk, fsc);
}

// Round 3
// 115.922 us; speedup vs baseline: 2.5431x; 1.0063x over previous
//
#include <hip/hip_runtime.h>
#include <hip/hip_bf16.h>
#include <math.h>

// Problem constants (from reference)
#define BB 512
#define SS 4096
#define DD 128
#define VV 6
#define KK 409   // max(1, int(4096*0.1))

// R2: single fused kernel. R1 profile showed dur_us includes harness fills
// (~45 us floor) + precompute ~40 us (single-block latency island, cold L3
// each iter) + row ~28 us. Fusion: every block redundantly computes the
// 6-token MLP (160k FMA = free), weights shared via L2/L3. LDS buffer reuse
// (W1 -> A1 -> A2 through one 32 KB buffer) keeps static LDS ~50 KB ->
// 2 blocks/CU.
__global__ __launch_bounds__(256) void fused_kernel(
    const int* __restrict__ x,
    const float* __restrict__ emb,
    const float* __restrict__ W1, const float* __restrict__ b1,
    const float* __restrict__ W2, const float* __restrict__ b2,
    const float* __restrict__ W3, const float* __restrict__ b3,
    const float* __restrict__ A1, const float* __restrict__ a1,
    const float* __restrict__ A2, const float* __restrict__ a2,
    const float* __restrict__ C1, const float* __restrict__ c1,
    const float* __restrict__ C2, const float* __restrict__ c2,
    float* __restrict__ pred, float* __restrict__ topk, float* __restrict__ fsc)
{
    __shared__ float sBuf[DD * 64];   // 32 KB: holds W1, then A1, then A2([64][128])
    __shared__ float sW2[64 * 32];    // 8 KB
    __shared__ float sE[VV * DD];     // 3 KB
    __shared__ float sW3[32];
    __shared__ float sb1[64], sb2[32], sa1[64], sa2[DD];
    __shared__ float sb3;
    __shared__ float sh1[VV * 64];    // h1, later reused as g
    __shared__ float sh2[VV * 32];
    __shared__ float sc[VV];
    __shared__ float att_s[VV * DD];  // 3 KB
    __shared__ int   waveTot[4 * VV];
    __shared__ float pooled[DD];
    __shared__ float hcls[64];

    const int tid  = threadIdx.x;   // 256
    const int b    = blockIdx.x;    // one batch row per block
    const int lane = tid & 63;
    const int w    = tid >> 6;

    // issue x loads FIRST so HBM latency overlaps weight staging + MLP phases
    const int base = b * SS + tid * 16;
    const int4* xp = (const int4*)(x + base);
    int4 xv[4];
    #pragma unroll
    for (int q = 0; q < 4; ++q) xv[q] = xp[q];

    // ---- S0: stage W1 + W2 + emb + small vectors
    {
        const float* srcs[7] = { W1, W2, emb, b1, b2, a1, a2 };
        float*       dsts[7] = { sBuf, sW2, sE, sb1, sb2, sa1, sa2 };
        const int    ns[7]   = { 8192, 2048, VV * DD, 64, 32, 64, DD };
        #pragma unroll
        for (int a = 0; a < 7; ++a) {
            const float4* s4 = (const float4*)srcs[a];
            float4* d4 = (float4*)dsts[a];
            const int n4 = ns[a] >> 2;
            for (int i = tid; i < n4; i += 256) d4[i] = s4[i];
        }
        if (tid < 32) sW3[tid] = W3[tid];
        if (tid == 0) sb3 = b3[0];
    }
    __syncthreads();

    // ---- S1: h1[t][o] = relu(E[t]·W1[:,o])   (384 units)
    for (int u = tid; u < VV * 64; u += 256) {
        const int t = u >> 6, o = u & 63;
        float acc = sb1[o];
        const float* ev = &sE[t * DD];
        #pragma unroll 8
        for (int d = 0; d < DD; ++d) acc += ev[d] * sBuf[d * 64 + o];
        sh1[u] = fmaxf(acc, 0.f);
    }
    __syncthreads();

    // ---- S2: stage A1 into sBuf (W1 dead) ; h2 = relu(h1·W2)  (192 units)
    {
        const float4* s4 = (const float4*)A1;
        float4* d4 = (float4*)sBuf;
        for (int i = tid; i < 2048; i += 256) d4[i] = s4[i];
    }
    for (int u = tid; u < VV * 32; u += 256) {
        const int t = u >> 5, o = u & 31;
        float acc = sb2[o];
        #pragma unroll 8
        for (int j = 0; j < 64; ++j) acc += sh1[t * 64 + j] * sW2[j * 32 + o];
        sh2[u] = fmaxf(acc, 0.f);
    }
    __syncthreads();

    // ---- S3: scores (6 units) ; g[t][o] = relu(E[t]·A1[:,o]) into sh1 (384 units)
    if (tid < VV) {
        float s = sb3;
        #pragma unroll
        for (int j = 0; j < 32; ++j) s += sh2[tid * 32 + j] * sW3[j];
        sc[tid] = 1.f / (1.f + expf(-s));
    }
    for (int u = tid; u < VV * 64; u += 256) {
        const int t = u >> 6, o = u & 63;
        float acc = sa1[o];
        const float* ev = &sE[t * DD];
        #pragma unroll 8
        for (int d = 0; d < DD; ++d) acc += ev[d] * sBuf[d * 64 + o];
        sh1[u] = fmaxf(acc, 0.f);   // sh1 now holds g (h1 dead after S2)
    }
    __syncthreads();

    // ---- S4: stage A2 into sBuf (A1 dead) ; unpack x ; write final_scores
    {
        const float4* s4 = (const float4*)A2;
        float4* d4 = (float4*)sBuf;
        for (int i = tid; i < 2048; i += 256) d4[i] = s4[i];
    }
    int vals[16];
    #pragma unroll
    for (int q = 0; q < 4; ++q) {
        vals[q*4+0] = xv[q].x; vals[q*4+1] = xv[q].y;
        vals[q*4+2] = xv[q].z; vals[q*4+3] = xv[q].w;
    }
    {
        float4* op = (float4*)(fsc + base);
        #pragma unroll
        for (int q = 0; q < 4; ++q) {
            float4 o;
            o.x = sc[vals[q*4+0]];
            o.y = sc[vals[q*4+1]];
            o.z = sc[vals[q*4+2]];
            o.w = sc[vals[q*4+3]];
            op[q] = o;
        }
    }
    int lc[VV];
    #pragma unroll
    for (int t = 0; t < VV; ++t) {
        int c = 0;
        #pragma unroll
        for (int i = 0; i < 16; ++i) c += (vals[i] == t) ? 1 : 0;
        lc[t] = c;
    }
    __syncthreads();

    // ---- S5: att[t][o] = a2[o] + g[t]·A2[:,o]  (768 units) ; wave scans
    for (int u = tid; u < VV * DD; u += 256) {
        const int t = u >> 7, o = u & 127;
        float acc = sa2[o];
        #pragma unroll 8
        for (int j = 0; j < 64; ++j) acc += sh1[t * 64 + j] * sBuf[j * DD + o];
        att_s[u] = acc;
    }
    int excl[VV];
    #pragma unroll
    for (int t = 0; t < VV; ++t) {
        int v = lc[t];
        #pragma unroll
        for (int off = 1; off < 64; off <<= 1) {
            int u = __shfl_up(v, off, 64);
            if (lane >= off) v += u;
        }
        excl[t] = v - lc[t];
        if (lane == 63) waveTot[w * VV + t] = v;
    }
    __syncthreads();

    // ---- cross-wave totals, token priority, per-token budgets
    int rowTot[VV], woff[VV];
    #pragma unroll
    for (int t = 0; t < VV; ++t) {
        int a0 = waveTot[0*VV+t], a1v = waveTot[1*VV+t];
        int a2v = waveTot[2*VV+t], a3v = waveTot[3*VV+t];
        rowTot[t] = a0 + a1v + a2v + a3v;
        int wo = 0;
        if (w > 0) wo += a0;
        if (w > 1) wo += a1v;
        if (w > 2) wo += a2v;
        woff[t] = wo;
    }
    float s_reg[VV];
    #pragma unroll
    for (int t = 0; t < VV; ++t) s_reg[t] = sc[t];
    int pri[VV];
    #pragma unroll
    for (int t = 0; t < VV; ++t) {
        int p = 0;
        #pragma unroll
        for (int u = 0; u < VV; ++u)
            p += ((s_reg[u] > s_reg[t]) || ((s_reg[u] == s_reg[t]) && (u < t))) ? 1 : 0;
        pri[t] = p;
    }
    int start[VV], m[VV];
    #pragma unroll
    for (int t = 0; t < VV; ++t) {
        int cb = 0;
        #pragma unroll
        for (int u = 0; u < VV; ++u)
            cb += (pri[u] < pri[t]) ? rowTot[u] : 0;
        int mm = KK - cb;
        mm = (mm < 0) ? 0 : mm;
        mm = (mm > rowTot[t]) ? rowTot[t] : mm;
        m[t] = mm;
        start[t] = cb + woff[t] + excl[t];
    }

    // ---- emit selected indices (token-outer keeps register indexing static)
    #pragma unroll
    for (int t = 0; t < VV; ++t) {
        int pos = start[t];
        #pragma unroll
        for (int i = 0; i < 16; ++i) {
            if (vals[i] == t) {
                if (pos < KK) topk[b * KK + pos] = (float)(tid * 16 + i);
                pos++;
            }
        }
    }

    // ---- pooled = sum_t m_t * att_t / K ; classifier
    if (tid < DD) {
        float acc = 0.f;
        #pragma unroll
        for (int t = 0; t < VV; ++t) acc += (float)m[t] * att_s[t * DD + tid];
        pooled[tid] = acc * (1.0f / (float)KK);
    }
    __syncthreads();
    if (tid < 64) {
        float acc = c1[tid];
        #pragma unroll 8
        for (int d = 0; d < DD; ++d) acc += pooled[d] * C1[d * 64 + tid];
        hcls[tid] = fmaxf(acc, 0.f);
    }
    __syncthreads();
    if (tid == 0) {
        float s = c2[0];
        #pragma unroll 8
        for (int j = 0; j < 64; ++j) s += hcls[j] * C2[j];
        pred[b] = 1.f / (1.f + expf(-s));
    }
}

extern "C" void kernel_launch(void* const* d_in, const int* in_sizes, int n_in,
                              void* d_out, int out_size, void* d_ws, size_t ws_size,
                              hipStream_t stream)
{
    (void)in_sizes; (void)n_in; (void)out_size; (void)d_ws; (void)ws_size;
    const int*   x   = (const int*)d_in[0];
    const float* emb = (const float*)d_in[1];
    const float* W1  = (const float*)d_in[2];
    const float* b1  = (const float*)d_in[3];
    const float* W2  = (const float*)d_in[4];
    const float* b2  = (const float*)d_in[5];
    const float* W3  = (const float*)d_in[6];
    const float* b3  = (const float*)d_in[7];
    const float* A1  = (const float*)d_in[8];
    const float* a1  = (const float*)d_in[9];
    const float* A2  = (const float*)d_in[10];
    const float* a2  = (const float*)d_in[11];
    const float* C1  = (const float*)d_in[12];
    const float* c1  = (const float*)d_in[13];
    const float* C2  = (const float*)d_in[14];
    const float* c2  = (const float*)d_in[15];

    float* out  = (float*)d_out;
    float* pred = out;                 // [B]
    float* topk = out + BB;            // [B,K] (indices as float32 — exact to 2^24)
    float* fsc  = out + BB + BB*KK;    // [B,S]

    fused_kernel<<<BB, 256, 0, stream>>>(x, emb, W1, b1, W2, b2, W3, b3,
                                         A1, a1, A2, a2, C1, c1, C2, c2,
                                         pred, topk, fsc);
}

// Round 4
// 115.637 us; speedup vs baseline: 2.5494x; 1.0025x over previous
//
#include <hip/hip_runtime.h>
#include <hip/hip_bf16.h>
#include <math.h>

// Problem constants (from reference)
#define BB 512
#define SS 4096
#define DD 128
#define VV 6
#define KK 409   // max(1, int(4096*0.1))

// d_ws layout (floats): [0..5] score_t ; [16..16+6*128) att_t rows

// R3 accounting (dispatch-ID spacing): each timed iter = 16 restores +
// 256MiB ws poison fill (~41us) + out fill + kernel(s), serialized.
// Harness floor ~85-100us. This round: leanest possible kernels to bound
// our own share. Split structure (rows must not stage 107KB weights each).

__global__ __launch_bounds__(256) void precompute_kernel(
    const float* __restrict__ emb,
    const float* __restrict__ W1, const float* __restrict__ b1,
    const float* __restrict__ W2, const float* __restrict__ b2,
    const float* __restrict__ W3, const float* __restrict__ b3,
    const float* __restrict__ A1, const float* __restrict__ a1,
    const float* __restrict__ A2, const float* __restrict__ a2,
    float* __restrict__ ws)
{
    __shared__ float sW1[DD * 64];
    __shared__ float sA1[DD * 64];
    __shared__ float sW2[64 * 32];
    __shared__ float sA2[64 * DD];
    __shared__ float sE[VV * DD];
    __shared__ float sW3[32];
    __shared__ float sb1[64], sb2[32], sa1[64], sa2[DD];
    __shared__ float sh1[VV * 64], sg[VV * 64], sh2[VV * 32];
    __shared__ float sb3;

    const int tid = threadIdx.x; // 256

    {
        const float* srcs[9] = { W1, A1, W2, A2, emb, b1, b2, a1, a2 };
        float*       dsts[9] = { sW1, sA1, sW2, sA2, sE, sb1, sb2, sa1, sa2 };
        const int    ns[9]   = { 8192, 8192, 2048, 8192, VV*DD, 64, 32, 64, DD };
        for (int a = 0; a < 9; ++a) {
            const float4* s4 = (const float4*)srcs[a];
            float4* d4 = (float4*)dsts[a];
            const int n4 = ns[a] >> 2;
            for (int i = tid; i < n4; i += 256) d4[i] = s4[i];
        }
        if (tid < 32) sW3[tid] = W3[tid];
        if (tid == 0) sb3 = b3[0];
    }
    __syncthreads();

    for (int u = tid; u < 768; u += 256) {
        const int isH = (u < 384) ? 1 : 0;
        const int v = isH ? u : (u - 384);
        const int t = v >> 6, o = v & 63;
        const float* wcol = isH ? sW1 : sA1;
        float acc = isH ? sb1[o] : sa1[o];
        const float* ev = &sE[t * DD];
        #pragma unroll 8
        for (int d = 0; d < DD; ++d) acc += ev[d] * wcol[d * 64 + o];
        acc = fmaxf(acc, 0.f);
        if (isH) sh1[v] = acc; else sg[v] = acc;
    }
    __syncthreads();

    for (int u = tid; u < VV * 32; u += 256) {
        const int t = u >> 5, o = u & 31;
        float acc = sb2[o];
        #pragma unroll 8
        for (int j = 0; j < 64; ++j) acc += sh1[t * 64 + j] * sW2[j * 32 + o];
        sh2[u] = fmaxf(acc, 0.f);
    }
    __syncthreads();

    for (int u = tid; u < 6 + VV * DD; u += 256) {
        if (u < 6) {
            float s = sb3;
            #pragma unroll
            for (int j = 0; j < 32; ++j) s += sh2[u * 32 + j] * sW3[j];
            ws[u] = 1.f / (1.f + expf(-s));
        } else {
            const int v = u - 6;
            const int t = v >> 7, o = v & 127;
            float acc = sa2[o];
            #pragma unroll 8
            for (int j = 0; j < 64; ++j) acc += sg[t * 64 + j] * sA2[j * DD + o];
            ws[16 + v] = acc;
        }
    }
}

// 512 threads x 8 tokens/thread: halves per-thread serial VALU (emit loop
// 96->48 predicated iters) vs R2's 256x16, doubles wave parallelism/block.
__global__ __launch_bounds__(512) void row_kernel(
    const int* __restrict__ x,
    const float* __restrict__ ws,
    const float* __restrict__ C1, const float* __restrict__ c1,
    const float* __restrict__ C2, const float* __restrict__ c2,
    float* __restrict__ pred, float* __restrict__ topk, float* __restrict__ fsc)
{
    __shared__ float sc[VV];
    __shared__ float att_s[VV * DD];
    __shared__ int   waveTot[8 * VV];
    __shared__ float pooled[DD];
    __shared__ float hcls[64];

    const int tid  = threadIdx.x;   // 512
    const int b    = blockIdx.x;
    const int lane = tid & 63;
    const int w    = tid >> 6;      // 0..7

    // x loads first: the only HBM-latency-critical reads
    const int base = b * SS + tid * 8;
    const int4* xp = (const int4*)(x + base);
    int4 xv0 = xp[0], xv1 = xp[1];

    if (tid < VV) sc[tid] = ws[tid];
    for (int i = tid; i < VV * DD; i += 512) att_s[i] = ws[16 + i];
    __syncthreads();

    int vals[8];
    vals[0]=xv0.x; vals[1]=xv0.y; vals[2]=xv0.z; vals[3]=xv0.w;
    vals[4]=xv1.x; vals[5]=xv1.y; vals[6]=xv1.z; vals[7]=xv1.w;

    {
        float4* op = (float4*)(fsc + base);
        float4 o0, o1;
        o0.x = sc[vals[0]]; o0.y = sc[vals[1]]; o0.z = sc[vals[2]]; o0.w = sc[vals[3]];
        o1.x = sc[vals[4]]; o1.y = sc[vals[5]]; o1.z = sc[vals[6]]; o1.w = sc[vals[7]];
        op[0] = o0; op[1] = o1;
    }

    int lc[VV];
    #pragma unroll
    for (int t = 0; t < VV; ++t) {
        int c = 0;
        #pragma unroll
        for (int i = 0; i < 8; ++i) c += (vals[i] == t) ? 1 : 0;
        lc[t] = c;
    }

    // per-wave inclusive scan per token
    int excl[VV];
    #pragma unroll
    for (int t = 0; t < VV; ++t) {
        int v = lc[t];
        #pragma unroll
        for (int off = 1; off < 64; off <<= 1) {
            int u = __shfl_up(v, off, 64);
            if (lane >= off) v += u;
        }
        excl[t] = v - lc[t];
        if (lane == 63) waveTot[w * VV + t] = v;
    }
    __syncthreads();

    int rowTot[VV], woff[VV];
    #pragma unroll
    for (int t = 0; t < VV; ++t) {
        int tot = 0, wo = 0;
        #pragma unroll
        for (int j = 0; j < 8; ++j) {
            int c = waveTot[j * VV + t];
            tot += c;
            if (j < 1) {} // keep compiler from folding wrongly
            wo += (j < w) ? c : 0;
        }
        rowTot[t] = tot;
        woff[t] = wo;
    }

    // token priority (score desc, index asc) — static register indexing only
    float s_reg[VV];
    #pragma unroll
    for (int t = 0; t < VV; ++t) s_reg[t] = sc[t];
    int pri[VV];
    #pragma unroll
    for (int t = 0; t < VV; ++t) {
        int p = 0;
        #pragma unroll
        for (int u = 0; u < VV; ++u)
            p += ((s_reg[u] > s_reg[t]) || ((s_reg[u] == s_reg[t]) && (u < t))) ? 1 : 0;
        pri[t] = p;
    }
    int start[VV], m[VV];
    #pragma unroll
    for (int t = 0; t < VV; ++t) {
        int cb = 0;
        #pragma unroll
        for (int u = 0; u < VV; ++u)
            cb += (pri[u] < pri[t]) ? rowTot[u] : 0;
        int mm = KK - cb;
        mm = (mm < 0) ? 0 : mm;
        mm = (mm > rowTot[t]) ? rowTot[t] : mm;
        m[t] = mm;
        start[t] = cb + woff[t] + excl[t];
    }

    // emit selected indices
    #pragma unroll
    for (int t = 0; t < VV; ++t) {
        int pos = start[t];
        #pragma unroll
        for (int i = 0; i < 8; ++i) {
            if (vals[i] == t) {
                if (pos < KK) topk[b * KK + pos] = (float)(tid * 8 + i);
                pos++;
            }
        }
    }

    // pooled + classifier
    if (tid < DD) {
        float acc = 0.f;
        #pragma unroll
        for (int t = 0; t < VV; ++t) acc += (float)m[t] * att_s[t * DD + tid];
        pooled[tid] = acc * (1.0f / (float)KK);
    }
    __syncthreads();
    if (tid < 64) {
        float acc = c1[tid];
        #pragma unroll 8
        for (int d = 0; d < DD; ++d) acc += pooled[d] * C1[d * 64 + tid];
        hcls[tid] = fmaxf(acc, 0.f);
    }
    __syncthreads();
    if (tid == 0) {
        float s = c2[0];
        #pragma unroll 8
        for (int j = 0; j < 64; ++j) s += hcls[j] * C2[j];
        pred[b] = 1.f / (1.f + expf(-s));
    }
}

extern "C" void kernel_launch(void* const* d_in, const int* in_sizes, int n_in,
                              void* d_out, int out_size, void* d_ws, size_t ws_size,
                              hipStream_t stream)
{
    (void)in_sizes; (void)n_in; (void)out_size; (void)ws_size;
    const int*   x   = (const int*)d_in[0];
    const float* emb = (const float*)d_in[1];
    const float* W1  = (const float*)d_in[2];
    const float* b1  = (const float*)d_in[3];
    const float* W2  = (const float*)d_in[4];
    const float* b2  = (const float*)d_in[5];
    const float* W3  = (const float*)d_in[6];
    const float* b3  = (const float*)d_in[7];
    const float* A1  = (const float*)d_in[8];
    const float* a1  = (const float*)d_in[9];
    const float* A2  = (const float*)d_in[10];
    const float* a2  = (const float*)d_in[11];
    const float* C1  = (const float*)d_in[12];
    const float* c1  = (const float*)d_in[13];
    const float* C2  = (const float*)d_in[14];
    const float* c2  = (const float*)d_in[15];

    float* out  = (float*)d_out;
    float* pred = out;                 // [B]
    float* topk = out + BB;            // [B,K] (indices as float32 — exact)
    float* fsc  = out + BB + BB*KK;    // [B,S]
    float* ws   = (float*)d_ws;

    precompute_kernel<<<1, 256, 0, stream>>>(emb, W1, b1, W2, b2, W3, b3,
                                             A1, a1, A2, a2, ws);
    row_kernel<<<BB, 512, 0, stream>>>(x, ws, C1, c1, C2, c2, pred, topk, fsc);
}